// Round 6
// baseline (575.284 us; speedup 1.0000x reference)
//
#include <hip/hip_runtime.h>
#include <hip/hip_bf16.h>

typedef short s16x8 __attribute__((ext_vector_type(8)));      // 8 bf16 (4 VGPRs)
typedef float f32x16 __attribute__((ext_vector_type(16)));
typedef unsigned short us8 __attribute__((ext_vector_type(8)));

#define HE   1024
#define SEQ  4096
#define NBAT 32
#define BM   64      // rows per block
#define BK   32      // k per chunk
#define NC   32      // HE / BK

__device__ __forceinline__ unsigned short f2bf(float f) {
    unsigned u = __builtin_bit_cast(unsigned, f);
    u += 0x7FFFu + ((u >> 16) & 1u);
    return (unsigned short)(u >> 16);
}

__device__ __forceinline__ float tanh_fast(float x) {
    float e = __expf(2.0f * x);
    return 1.0f - 2.0f / (e + 1.0f);
}

// async global->LDS, 16B per lane; LDS dest is wave-uniform base + lane*16
__device__ __forceinline__ void gload_lds16(const void* g, void* l) {
    __builtin_amdgcn_global_load_lds(
        (const __attribute__((address_space(1))) unsigned int*)g,
        (__attribute__((address_space(3))) unsigned int*)l,
        16, 0, 0);
}

// ---- h_proj partials
__global__ void k_hproj(const float* __restrict__ hidden, const float* __restrict__ W,
                        float* __restrict__ cpart) {
    int b = blockIdx.x >> 3, kc = blockIdx.x & 7;
    int h = threadIdx.x;
    const float* hv = hidden + (NBAT + b) * HE;   // hidden[-1]
    int k0 = kc * 128;
    float acc = 0.f;
    for (int j = 0; j < 128; ++j)
        acc = fmaf(hv[k0 + j], W[(k0 + j) * HE + h], acc);
    cpart[(b * 8 + kc) * HE + h] = acc;
}

__global__ void k_cfinal(const float* __restrict__ cpart, const float* __restrict__ b_attn,
                         float* __restrict__ c) {
    int b = blockIdx.x, h = threadIdx.x;
    float s = b_attn[h];
    #pragma unroll
    for (int kc = 0; kc < 8; ++kc) s += cpart[(b * 8 + kc) * HE + h];
    c[b * HE + h] = s;
}

// ---- pack W_e (= W_attn[He:]) into 32x32x16 MFMA B-fragment order:
// frag F = kb2*32+cf (1 KB): lane l holds bf16 W_e[kb2*16+(l>>5)*8+i][cf*32+(l&31)]
__global__ void k_pack(const float* __restrict__ W, unsigned short* __restrict__ Wp) {
    int gid = blockIdx.x * blockDim.x + threadIdx.x;   // 131072 threads
    int l = gid & 63, cf = (gid >> 6) & 31, kb2 = gid >> 11;
    int krow = HE + kb2 * 16 + ((l >> 5) * 8);
    int col  = cf * 32 + (l & 31);
    us8 v;
    #pragma unroll
    for (int i = 0; i < 8; ++i) v[i] = f2bf(W[(krow + i) * HE + col]);
    *(us8*)(Wp + (long)gid * 8) = v;
}

// ---- main fused kernel: 64 rows x 1024 cols per block, 512 threads (8 waves);
//      B staged via global_load_lds (linear, fragment-ordered), E reg-staged;
//      2-phase pipeline: STAGE(g+1) -> compute(g) -> drain+barrier
__global__ __launch_bounds__(512, 2) void k_main(
    const float* __restrict__ E, const unsigned short* __restrict__ Wp,
    const float* __restrict__ C, const float* __restrict__ VW,
    float* __restrict__ scores)
{
    __shared__ unsigned short Bbuf[2][32768];   // 2 x 64 KB: 64 frags x 1 KB, linear
    __shared__ unsigned short Ebuf[2][2048];    // 2 x 4 KB: 64 rows x 32 k bf16, swizzled
    __shared__ float smred[BM][8];

    const int tid  = threadIdx.x;
    const int lane = tid & 63;
    const int wv   = tid >> 6;           // wave 0..7, col-frags wv*4..+3
    const int m0   = blockIdx.x * BM;
    const int bb   = m0 >> 12;
    const int l31  = lane & 31, lh = lane >> 5;

    // E staging: 512 threads x 4 floats = 64 rows x 32 k
    const int s_row = tid >> 3;
    const int s_kq  = tid & 7;           // 4-float group
    const float* gE = E + (long)(m0 + s_row) * HE + s_kq * 4;
    // LDS E: row stride 64 B, 4 x 16B units, unit ^= row&3 (2-way residual = free)
    const int e_wo = s_row * 64 + (((s_kq >> 1) ^ (s_row & 3)) << 4) + (s_kq & 1) * 8;

    // A-frag read: row = rf*32 + l31, k-unit = stp*2 + lh, unit ^= row&3
    const int a_o0 = l31 * 64;
    const int a_o1 = (32 + l31) * 64;
    const int a_sw = l31 & 3;

    const char* WpB = (const char*)Wp;

    f32x16 acc[2][4];
    #pragma unroll
    for (int rf = 0; rf < 2; ++rf)
        #pragma unroll
        for (int cfi = 0; cfi < 4; ++cfi)
            #pragma unroll
            for (int e = 0; e < 16; ++e) acc[rf][cfi][e] = 0.f;

#define STAGE_B(pb, g1) do {                                                     \
    const char* src_ = WpB + (((long)(g1) * 64 + wv * 8) << 10) + (lane << 4);   \
    char* dst_ = (char*)&Bbuf[pb][0] + ((wv * 8) << 10);                         \
    _Pragma("unroll")                                                            \
    for (int r_ = 0; r_ < 8; ++r_)                                               \
        gload_lds16(src_ + (r_ << 10), dst_ + (r_ << 10));                       \
} while (0)

#define E_WRITE(pb) do {                                                         \
    ushort4 w_;                                                                  \
    w_.x = f2bf(evq.x); w_.y = f2bf(evq.y);                                      \
    w_.z = f2bf(evq.z); w_.w = f2bf(evq.w);                                      \
    *(ushort4*)((char*)&Ebuf[pb][0] + e_wo) = w_;                                \
} while (0)

#define AREAD(d0, d1, pb, stp) do {                                              \
    const int o_ = ((((stp) * 2 + lh) ^ a_sw) << 4);                             \
    d0 = *(const s16x8*)((const char*)&Ebuf[pb][0] + a_o0 + o_);                 \
    d1 = *(const s16x8*)((const char*)&Ebuf[pb][0] + a_o1 + o_);                 \
} while (0)

#define BREAD(bv, pb, stp)                                                       \
    _Pragma("unroll")                                                            \
    for (int cfi = 0; cfi < 4; ++cfi)                                            \
        bv[cfi] = *(const s16x8*)((const char*)&Bbuf[pb][0] +                    \
            (((stp) * 32 + wv * 4 + cfi) << 10) + (lane << 4));

#define MFMA8(a0_, a1_, bv) do {                                                 \
    __builtin_amdgcn_s_setprio(1);                                               \
    _Pragma("unroll")                                                            \
    for (int cfi = 0; cfi < 4; ++cfi)                                            \
        acc[0][cfi] = __builtin_amdgcn_mfma_f32_32x32x16_bf16(                   \
            a0_, bv[cfi], acc[0][cfi], 0, 0, 0);                                 \
    _Pragma("unroll")                                                            \
    for (int cfi = 0; cfi < 4; ++cfi)                                            \
        acc[1][cfi] = __builtin_amdgcn_mfma_f32_32x32x16_bf16(                   \
            a1_, bv[cfi], acc[1][cfi], 0, 0, 0);                                 \
    __builtin_amdgcn_s_setprio(0);                                               \
} while (0)

    float4 evq;

    // prologue: stage chunk 0
    evq = *(const float4*)(gE);
    STAGE_B(0, 0);
    E_WRITE(0);                  // compiler waits evq only (B loads newer)
    __syncthreads();             // drains B(0) gload_lds

    for (int g = 0; g < NC; ++g) {
        const int p = g & 1;
        s16x8 x0, x1, y0, y1, bs0[4], bs1[4];

        if (g + 1 < NC) {
            evq = *(const float4*)(gE + (g + 1) * BK);   // oldest in-flight
            STAGE_B(p ^ 1, g + 1);                       // 8 async loads -> other buf
        }

        AREAD(x0, x1, p, 0);
        BREAD(bs0, p, 0);
        AREAD(y0, y1, p, 1);
        BREAD(bs1, p, 1);
        MFMA8(x0, x1, bs0);
        MFMA8(y0, y1, bs1);

        if (g + 1 < NC) E_WRITE(p ^ 1);   // waits evq (counted vmcnt), writes other buf
        __syncthreads();                  // drains B(g+1) staging; full-chunk slack
    }

#undef STAGE_B
#undef E_WRITE
#undef AREAD
#undef BREAD
#undef MFMA8

    // fused epilogue: score[row] = sum_col v_w[col] * tanh(acc + c[b][col])
    float cv[4], vv[4];
    #pragma unroll
    for (int cfi = 0; cfi < 4; ++cfi) {
        int col = (wv * 4 + cfi) * 32 + l31;
        cv[cfi] = C[bb * HE + col];
        vv[cfi] = VW[col];
    }
    #pragma unroll
    for (int rf = 0; rf < 2; ++rf) {
        #pragma unroll
        for (int reg = 0; reg < 16; ++reg) {
            float pS = 0.f;
            #pragma unroll
            for (int cfi = 0; cfi < 4; ++cfi)
                pS += tanh_fast(acc[rf][cfi][reg] + cv[cfi]) * vv[cfi];
            pS += __shfl_xor(pS, 1);
            pS += __shfl_xor(pS, 2);
            pS += __shfl_xor(pS, 4);
            pS += __shfl_xor(pS, 8);
            pS += __shfl_xor(pS, 16);
            if (l31 == 0) {
                int row = rf * 32 + (reg & 3) + 8 * (reg >> 2) + 4 * lh;
                smred[row][wv] = pS;
            }
        }
    }
    __syncthreads();
    if (tid < BM) {
        float s = 0.f;
        #pragma unroll
        for (int ww = 0; ww < 8; ++ww) s += smred[tid][ww];
        scores[m0 + tid] = s;
    }
}

// ---- softmax over S=4096 per batch row
__global__ void k_softmax(const float* __restrict__ scores, float* __restrict__ out) {
    __shared__ float red[16];
    __shared__ float red2[16];
    int b = blockIdx.x, tid = threadIdx.x;
    const float* s = scores + b * SEQ;
    float v[4];
    float mx = -1e30f;
    #pragma unroll
    for (int j = 0; j < 4; ++j) { v[j] = s[tid + j * 1024]; mx = fmaxf(mx, v[j]); }
    #pragma unroll
    for (int off = 32; off; off >>= 1) mx = fmaxf(mx, __shfl_xor(mx, off));
    if ((tid & 63) == 0) red[tid >> 6] = mx;
    __syncthreads();
    mx = red[0];
    #pragma unroll
    for (int i = 1; i < 16; ++i) mx = fmaxf(mx, red[i]);
    float sum = 0.f;
    #pragma unroll
    for (int j = 0; j < 4; ++j) { v[j] = expf(v[j] - mx); sum += v[j]; }
    #pragma unroll
    for (int off = 32; off; off >>= 1) sum += __shfl_xor(sum, off);
    if ((tid & 63) == 0) red2[tid >> 6] = sum;
    __syncthreads();
    sum = 0.f;
    #pragma unroll
    for (int i = 0; i < 16; ++i) sum += red2[i];
    float inv = 1.0f / sum;
    #pragma unroll
    for (int j = 0; j < 4; ++j) out[b * SEQ + tid + j * 1024] = v[j] * inv;
}

extern "C" void kernel_launch(void* const* d_in, const int* in_sizes, int n_in,
                              void* d_out, int out_size, void* d_ws, size_t ws_size,
                              hipStream_t stream)
{
    const float* hidden = (const float*)d_in[0];
    const float* enc    = (const float*)d_in[1];
    const float* W      = (const float*)d_in[2];
    const float* b_attn = (const float*)d_in[3];
    const float* v_w    = (const float*)d_in[4];
    float* out          = (float*)d_out;

    char* ws = (char*)d_ws;
    unsigned short* Wp = (unsigned short*)(ws);                        // 2 MB packed bf16 W_e
    float* cpart       = (float*)(ws + (2u << 20));                    // 1 MB
    float* Cc          = (float*)(ws + (3u << 20));                    // 128 KB
    float* scores      = (float*)(ws + (3u << 20) + (128u << 10));     // 512 KB

    k_pack   <<<512, 256,  0, stream>>>(W, Wp);
    k_hproj  <<<256, 1024, 0, stream>>>(hidden, W, cpart);
    k_cfinal <<<32,  1024, 0, stream>>>(cpart, b_attn, Cc);
    k_main   <<<2048, 512, 0, stream>>>(enc, Wp, Cc, v_w, scores);
    k_softmax<<<32,  1024, 0, stream>>>(scores, out);
}

// Round 7
// 417.146 us; speedup vs baseline: 1.3791x; 1.3791x over previous
//
#include <hip/hip_runtime.h>
#include <hip/hip_bf16.h>

typedef short s16x8 __attribute__((ext_vector_type(8)));      // 8 bf16 (4 VGPRs)
typedef float f32x16 __attribute__((ext_vector_type(16)));
typedef unsigned short us8 __attribute__((ext_vector_type(8)));

#define HE    1024
#define SEQ   4096
#define NBAT  32
#define BM    64      // rows per block
#define KSUB  128     // k per subtile/group
#define NGRP  8       // HE / KSUB
#define NSTEP 8       // 16-k steps per group

__device__ __forceinline__ unsigned short f2bf(float f) {
    unsigned u = __builtin_bit_cast(unsigned, f);
    u += 0x7FFFu + ((u >> 16) & 1u);
    return (unsigned short)(u >> 16);
}

__device__ __forceinline__ float tanh_fast(float x) {
    float e = __expf(2.0f * x);
    return 1.0f - 2.0f / (e + 1.0f);
}

// barrier WITHOUT vmcnt drain: only LDS ops must be cross-wave visible;
// register-destined global loads stay in flight across it.
#define WG_SYNC() do {                                         \
    asm volatile("s_waitcnt lgkmcnt(0)" ::: "memory");         \
    __builtin_amdgcn_s_barrier();                              \
} while (0)

// ---- h_proj partials
__global__ void k_hproj(const float* __restrict__ hidden, const float* __restrict__ W,
                        float* __restrict__ cpart) {
    int b = blockIdx.x >> 3, kc = blockIdx.x & 7;
    int h = threadIdx.x;
    const float* hv = hidden + (NBAT + b) * HE;   // hidden[-1]
    int k0 = kc * 128;
    float acc = 0.f;
    for (int j = 0; j < 128; ++j)
        acc = fmaf(hv[k0 + j], W[(k0 + j) * HE + h], acc);
    cpart[(b * 8 + kc) * HE + h] = acc;
}

__global__ void k_cfinal(const float* __restrict__ cpart, const float* __restrict__ b_attn,
                         float* __restrict__ c) {
    int b = blockIdx.x, h = threadIdx.x;
    float s = b_attn[h];
    #pragma unroll
    for (int kc = 0; kc < 8; ++kc) s += cpart[(b * 8 + kc) * HE + h];
    c[b * HE + h] = s;
}

// ---- pack W_e (= W_attn[He:]) into 32x32x16 MFMA B-fragment order:
// frag f = kst*32+cf (1 KB): lane l holds bf16 W_e[kst*16+(l>>5)*8+i][cf*32+(l&31)]
__global__ void k_pack(const float* __restrict__ W, unsigned short* __restrict__ Wp) {
    int gid = blockIdx.x * blockDim.x + threadIdx.x;   // 131072 threads
    int l = gid & 63, cf = (gid >> 6) & 31, kst = gid >> 11;
    int krow = HE + kst * 16 + ((l >> 5) * 8);
    int col  = cf * 32 + (l & 31);
    us8 v;
    #pragma unroll
    for (int i = 0; i < 8; ++i) v[i] = f2bf(W[(krow + i) * HE + col]);
    *(us8*)(Wp + (long)gid * 8) = v;
}

// ---- main fused kernel: 64 rows x 1024 cols per block, 1024 threads (16 waves,
//      4 waves/SIMD), single K-pass, K pipelined in 8 subtile-groups;
//      per wave: acc[2][2] (64 regs), B reg-dbuf, E reg-staged 2 groups ahead
__global__ __launch_bounds__(1024, 4) void k_main(
    const float* __restrict__ E, const unsigned short* __restrict__ Wp,
    const float* __restrict__ C, const float* __restrict__ VW,
    float* __restrict__ scores)
{
    __shared__ unsigned short Asub[2][BM * KSUB];   // 2 x 16 KB, swizzled bf16 E subtile
    __shared__ float smred[BM][16];

    const int tid  = threadIdx.x;
    const int lane = tid & 63;
    const int wv   = tid >> 6;           // wave 0..15, col-frags wv*2, wv*2+1
    const int m0   = blockIdx.x * BM;
    const int bb   = m0 >> 12;
    const int l31  = lane & 31, lh = lane >> 5;

    // E staging: 1024 threads x 8 floats = 64 rows x 128 k per subtile
    const int s_row = tid >> 4;          // 0..63
    const int s_kc  = tid & 15;          // 16B-unit (8 bf16) within row
    const float* gEs = E + (long)(m0 + s_row) * HE + s_kc * 8;
    const int e_wo = s_row * 256 + ((s_kc ^ (s_row & 7)) << 4);

    // A-frag read: row = rf*32 + l31, unit = 2s+lh, unit ^= row&7
    const int a_sw = l31 & 7;
    const int a_r0 = l31 * 256;
    const int a_r1 = (32 + l31) * 256;

    // B: frag f = kst*32 + wv*2 + cfi -> byte f*1024 + lane*16
    const char* WpB = (const char*)Wp + (((long)(wv * 2)) << 10) + (lane << 4);

    f32x16 acc[2][2];
    #pragma unroll
    for (int rf = 0; rf < 2; ++rf)
        #pragma unroll
        for (int cf = 0; cf < 2; ++cf)
            #pragma unroll
            for (int e = 0; e < 16; ++e) acc[rf][cf][e] = 0.f;

#define LOADB(dst, kst) do {                                                     \
    dst[0] = *(const s16x8*)(WpB + (((long)(kst) * 32 + 0) << 10));              \
    dst[1] = *(const s16x8*)(WpB + (((long)(kst) * 32 + 1) << 10));              \
} while (0)

#define AREAD(buf, s) do {                                                       \
    const char* Ab_ = (const char*)&Asub[buf][0];                                \
    const int o_ = (((2 * (s) + lh)) ^ a_sw) << 4;                               \
    a0 = *(const s16x8*)(Ab_ + a_r0 + o_);                                       \
    a1 = *(const s16x8*)(Ab_ + a_r1 + o_);                                       \
} while (0)

#define MFMA4(bv) do {                                                           \
    __builtin_amdgcn_s_setprio(1);                                               \
    acc[0][0] = __builtin_amdgcn_mfma_f32_32x32x16_bf16(a0, bv[0], acc[0][0], 0, 0, 0); \
    acc[0][1] = __builtin_amdgcn_mfma_f32_32x32x16_bf16(a0, bv[1], acc[0][1], 0, 0, 0); \
    acc[1][0] = __builtin_amdgcn_mfma_f32_32x32x16_bf16(a1, bv[0], acc[1][0], 0, 0, 0); \
    acc[1][1] = __builtin_amdgcn_mfma_f32_32x32x16_bf16(a1, bv[1], acc[1][1], 0, 0, 0); \
    __builtin_amdgcn_s_setprio(0);                                               \
} while (0)

#define EV_LOAD(vA, vB, g2) do {                                                 \
    vA = *(const float4*)(gEs + (g2) * KSUB);                                    \
    vB = *(const float4*)(gEs + (g2) * KSUB + 4);                                \
} while (0)

#define EV_WRITE(vA, vB, buf) do {                                               \
    us8 w_;                                                                      \
    w_[0]=f2bf(vA.x); w_[1]=f2bf(vA.y); w_[2]=f2bf(vA.z); w_[3]=f2bf(vA.w);      \
    w_[4]=f2bf(vB.x); w_[5]=f2bf(vB.y); w_[6]=f2bf(vB.z); w_[7]=f2bf(vB.w);      \
    *(us8*)((char*)&Asub[buf][0] + e_wo) = w_;                                   \
} while (0)

    s16x8 bE[2], bO[2], a0, a1;
    float4 eA0, eA1, eB0, eB1;

    // prologue: issue subtile 0 and 1 loads; B step 0; write subtile 0
    EV_LOAD(eA0, eA1, 0);
    EV_LOAD(eB0, eB1, 1);
    LOADB(bE, 0);
    EV_WRITE(eA0, eA1, 0);       // waits eA only (one prologue HBM latency)
    WG_SYNC();

    #pragma unroll
    for (int g = 0; g < NGRP; ++g) {
        const int buf = g & 1;

        #pragma unroll
        for (int s = 0; s < NSTEP; ++s) {
            int nk = g * NSTEP + s + 1;
            if (nk > 63) nk = 63;            // tail clamp (data unused)
            if ((s & 1) == 0) {
                LOADB(bO, nk);
                AREAD(buf, s);
                MFMA4(bE);
            } else {
                LOADB(bE, nk);
                AREAD(buf, s);
                MFMA4(bO);
            }
        }

        // group tail: issue E(g+2) AFTER all this group's B issues; write E(g+1)
        if (g < NGRP - 1) {
            if ((g & 1) == 0) {
                if (g < NGRP - 2) EV_LOAD(eA0, eA1, g + 2);
                EV_WRITE(eB0, eB1, 1);       // subtile g+1 -> buf 1
            } else {
                if (g < NGRP - 2) EV_LOAD(eB0, eB1, g + 2);
                EV_WRITE(eA0, eA1, 0);       // subtile g+1 -> buf 0
            }
            __builtin_amdgcn_sched_barrier(0);
            WG_SYNC();
        }
    }

#undef LOADB
#undef AREAD
#undef MFMA4
#undef EV_LOAD
#undef EV_WRITE

    // fused epilogue: score[row] = sum_col v_w[col] * tanh(acc + c[b][col])
    float cv[2], vv[2];
    #pragma unroll
    for (int cf = 0; cf < 2; ++cf) {
        int col = (wv * 2 + cf) * 32 + l31;
        cv[cf] = C[bb * HE + col];
        vv[cf] = VW[col];
    }
    #pragma unroll
    for (int rf = 0; rf < 2; ++rf) {
        #pragma unroll
        for (int reg = 0; reg < 16; ++reg) {
            float pS = 0.f;
            #pragma unroll
            for (int cf = 0; cf < 2; ++cf)
                pS += tanh_fast(acc[rf][cf][reg] + cv[cf]) * vv[cf];
            pS += __shfl_xor(pS, 1);
            pS += __shfl_xor(pS, 2);
            pS += __shfl_xor(pS, 4);
            pS += __shfl_xor(pS, 8);
            pS += __shfl_xor(pS, 16);
            if (l31 == 0) {
                int row = rf * 32 + (reg & 3) + 8 * (reg >> 2) + 4 * lh;
                smred[row][wv] = pS;
            }
        }
    }
    __syncthreads();
    if (tid < BM) {
        float s = 0.f;
        #pragma unroll
        for (int ww = 0; ww < 16; ++ww) s += smred[tid][ww];
        scores[m0 + tid] = s;
    }
}

// ---- softmax over S=4096 per batch row
__global__ void k_softmax(const float* __restrict__ scores, float* __restrict__ out) {
    __shared__ float red[16];
    __shared__ float red2[16];
    int b = blockIdx.x, tid = threadIdx.x;
    const float* s = scores + b * SEQ;
    float v[4];
    float mx = -1e30f;
    #pragma unroll
    for (int j = 0; j < 4; ++j) { v[j] = s[tid + j * 1024]; mx = fmaxf(mx, v[j]); }
    #pragma unroll
    for (int off = 32; off; off >>= 1) mx = fmaxf(mx, __shfl_xor(mx, off));
    if ((tid & 63) == 0) red[tid >> 6] = mx;
    __syncthreads();
    mx = red[0];
    #pragma unroll
    for (int i = 1; i < 16; ++i) mx = fmaxf(mx, red[i]);
    float sum = 0.f;
    #pragma unroll
    for (int j = 0; j < 4; ++j) { v[j] = expf(v[j] - mx); sum += v[j]; }
    #pragma unroll
    for (int off = 32; off; off >>= 1) sum += __shfl_xor(sum, off);
    if ((tid & 63) == 0) red2[tid >> 6] = sum;
    __syncthreads();
    sum = 0.f;
    #pragma unroll
    for (int i = 0; i < 16; ++i) sum += red2[i];
    float inv = 1.0f / sum;
    #pragma unroll
    for (int j = 0; j < 4; ++j) out[b * SEQ + tid + j * 1024] = v[j] * inv;
}

extern "C" void kernel_launch(void* const* d_in, const int* in_sizes, int n_in,
                              void* d_out, int out_size, void* d_ws, size_t ws_size,
                              hipStream_t stream)
{
    const float* hidden = (const float*)d_in[0];
    const float* enc    = (const float*)d_in[1];
    const float* W      = (const float*)d_in[2];
    const float* b_attn = (const float*)d_in[3];
    const float* v_w    = (const float*)d_in[4];
    float* out          = (float*)d_out;

    char* ws = (char*)d_ws;
    unsigned short* Wp = (unsigned short*)(ws);                        // 2 MB packed bf16 W_e
    float* cpart       = (float*)(ws + (2u << 20));                    // 1 MB
    float* Cc          = (float*)(ws + (3u << 20));                    // 128 KB
    float* scores      = (float*)(ws + (3u << 20) + (128u << 10));     // 512 KB

    k_pack   <<<512, 256,  0, stream>>>(W, Wp);
    k_hproj  <<<256, 1024, 0, stream>>>(hidden, W, cpart);
    k_cfinal <<<32,  1024, 0, stream>>>(cpart, b_attn, Cc);
    k_main   <<<2048, 1024, 0, stream>>>(enc, Wp, Cc, v_w, scores);
    k_softmax<<<32,  1024, 0, stream>>>(scores, out);
}